// Round 17
// baseline (152.342 us; speedup 1.0000x reference)
//
#include <hip/hip_runtime.h>
#include <stdint.h>

typedef int   int32x4   __attribute__((ext_vector_type(4)));
typedef int   int32x16  __attribute__((ext_vector_type(16)));
typedef float floatx4   __attribute__((ext_vector_type(4)));

#define B_ROWS 131072
#define DK 512           // K (= D)
#define FN 512           // N (= F)
#define A_SCALE_F ((float)(127.0 / 6.0))

// fused-GEMM geometry: 512 blocks x 512 threads (8 waves). R13 structure with
// BMS 32->64: 4 barrier periods instead of 8 (each ~1.3-1.5us of drain/rejoin
// overhead a lone block per CU cannot hide). Register-neutral vs R13:
// vA[8]+vB[8] -> vA[16] (same 64 VGPR); Bf/acc unchanged; wave computes
// 2 row-halves x 2 col-panels sequentially (one acc[16] live at a time).
#define GBLK 512
#define GT   512
#define BMS  64
#define GTILES (B_ROWS / BMS / GBLK)   // 4

// ---------------- prepass: quantize weights into B-fragment layout -------------
__global__ void wq_quant_kernel(const float* __restrict__ kern,  // [DK][FN]
                                int8_t* __restrict__ wq,         // [FN][DK]
                                float* __restrict__ invcs) {     // [FN]
  __shared__ float smax[256];
  __shared__ float sscale[4];
  const int c = threadIdx.x & 3;         // col within block
  const int g = threadIdx.x >> 2;        // row-group 0..63 (8 rows each)
  const int col = blockIdx.x * 4 + c;

  float m = 0.f;
#pragma unroll
  for (int i = 0; i < 8; ++i) {
    m = fmaxf(m, fabsf(kern[(size_t)(g * 8 + i) * FN + col]));
  }
  smax[threadIdx.x] = m;
  __syncthreads();
  if (threadIdx.x < 4) {
    float mm = smax[threadIdx.x];
#pragma unroll 8
    for (int g2 = 1; g2 < 64; ++g2) mm = fmaxf(mm, smax[g2 * 4 + threadIdx.x]);
    const float wb = fmaxf(mm, 1e-6f);
    const float ws = 127.f / wb;               // f32 divide, matches jnp w_scale
    sscale[threadIdx.x] = ws;
    invcs[blockIdx.x * 4 + threadIdx.x] =
        (float)(1.0 / ((double)A_SCALE_F * (double)ws));
  }
  __syncthreads();
  const float ws = sscale[c];
  uint32_t* wq32 = (uint32_t*)(wq + (size_t)col * DK);
#pragma unroll
  for (int d = 0; d < 2; ++d) {                // 8 rows -> 2 packed words
    uint32_t p = 0;
#pragma unroll
    for (int j = 0; j < 4; ++j) {
      float v = kern[(size_t)(g * 8 + d * 4 + j) * FN + col] * ws;
      v = floorf(v + 0.5f);                    // AQT round: floor(v+0.5)
      v = fminf(fmaxf(v, -127.f), 127.f);
      p |= ((uint32_t)((int)v & 255)) << (8 * j);
    }
    wq32[g * 2 + d] = p;
  }
}

// ---------------- quantize 4 f32 -> packed int8 word ---------------------------
__device__ __forceinline__ uint32_t quant4(floatx4 v) {
  uint32_t p = 0;
#pragma unroll
  for (int j = 0; j < 4; ++j) {
    float q = floorf(v[j] * A_SCALE_F + 0.5f);   // AQT round: floor(v+0.5)
    q = fminf(fmaxf(q, -127.f), 127.f);
    p |= ((uint32_t)((int)q & 255)) << (8 * j);
  }
  return p;
}

__global__ __launch_bounds__(GT, 2)
void aqt_gemm_fused(const float* __restrict__ x,     // [B_ROWS][DK]
                    const int8_t* __restrict__ wq,   // [FN][DK]
                    const float* __restrict__ invcs, // [FN]
                    const float* __restrict__ bias,  // [FN]
                    float* __restrict__ out) {       // [B_ROWS][FN]
  __shared__ __align__(16) uint8_t xq[2][BMS * DK];  // 2 x 32 KB

  const int tid  = threadIdx.x;
  const int lane = tid & 63;
  const int wv   = tid >> 6;       // 0..7 -> col strip w*64
  const int l31  = lane & 31;
  const int l5   = lane >> 5;

  const int c4 = tid & 127;        // float4 col within a row
  const int rg = tid >> 7;         // 0..3 -> rows rg, rg+4, ..., rg+60

  // ---- B fragments into registers, once (256 KB, L2-hot): 2 panels ----
  const int col0 = wv * 64 + l31;
  const int col1 = col0 + 32;
  int32x4 Bf0[16], Bf1[16];
#pragma unroll
  for (int ks = 0; ks < 16; ++ks) {
    Bf0[ks] = *(const int32x4*)(wq + (size_t)col0 * DK + ks * 32 + l5 * 16);
    Bf1[ks] = *(const int32x4*)(wq + (size_t)col1 * DK + ks * 32 + l5 * 16);
  }
  const float inv0 = invcs[col0], bv0 = bias[col0];
  const float inv1 = invcs[col1], bv1 = bias[col1];

  const size_t row0 = (size_t)blockIdx.x * (GTILES * BMS);

  // issue the 16 f32 tile loads for the 64-row tile starting at row rt
#define LOADV(vdst, rt)                                                       \
  {                                                                           \
    const float* xg_ = x + (size_t)(rt) * DK;                                 \
    _Pragma("unroll")                                                         \
    for (int i_ = 0; i_ < 16; ++i_)                                           \
      vdst[i_] = *(const floatx4*)(xg_ + (size_t)(i_ * 4 + rg) * DK + c4 * 4);\
  }

  // quantize 16 granules into LDS buffer (XOR-swizzled; rows r and r+32 share
  // the (r&31) swizzle, matching the read side's l31-based XOR)
#define QWRITE(vsrc, bufp)                                                    \
  {                                                                           \
    _Pragma("unroll")                                                         \
    for (int i_ = 0; i_ < 16; ++i_) {                                         \
      const int r_ = i_ * 4 + rg;                                             \
      *(uint32_t*)(&(bufp)[r_ * DK + ((c4 * 4) ^ ((r_ & 31) << 4))]) =        \
          quant4(vsrc[i_]);                                                   \
    }                                                                         \
  }

  // one 32-col panel on one 32-row half (hof = 0 or 32); acc lives only inside
#define PANEL(Bf, colv, invv, bvv, bufp, rt, hof)                             \
  {                                                                           \
    int32x16 acc = (int32x16)(0);                                             \
    const uint8_t* aRow_ = (bufp) + ((hof) + l31) * DK;                       \
    _Pragma("unroll")                                                         \
    for (int ks_ = 0; ks_ < 16; ++ks_) {                                      \
      int32x4 a_ = *(const int32x4*)(aRow_ + ((ks_ * 32 + l5 * 16) ^ (l31 << 4))); \
      acc = __builtin_amdgcn_mfma_i32_32x32x32_i8(a_, Bf[ks_], acc, 0, 0, 0); \
    }                                                                         \
    _Pragma("unroll")                                                         \
    for (int r_ = 0; r_ < 16; ++r_) {                                         \
      const int rowl_ = (r_ & 3) + 8 * (r_ >> 2) + 4 * l5;                    \
      __builtin_nontemporal_store((float)acc[r_] * (invv) + (bvv),            \
                                  &out[((rt) + (hof) + rowl_) * FN + (colv)]);\
    }                                                                         \
  }

  floatx4 vA[16];

  // ---- prologue: tile 0 staged (startup stall, once) ----
  LOADV(vA, row0);
  QWRITE(vA, (&xq[0][0]));
  asm volatile("s_waitcnt lgkmcnt(0)" ::: "memory");
  __builtin_amdgcn_s_barrier();

#pragma unroll 1
  for (int t = 0; t < GTILES; ++t) {
    const size_t rowT = row0 + (size_t)t * BMS;
    const uint8_t* bufC = &xq[t & 1][0];
    uint8_t* bufN = &xq[(t & 1) ^ 1][0];
    const bool pf = (t + 1 < GTILES);

    // loads for t+1 first (oldest vmem; covered by 4 K-loops + 3 epilogues)
    if (pf) LOADV(vA, rowT + BMS);

    PANEL(Bf0, col0, inv0, bv0, bufC, rowT, 0);
    PANEL(Bf1, col1, inv1, bv1, bufC, rowT, 0);
    PANEL(Bf0, col0, inv0, bv0, bufC, rowT, 32);
    PANEL(Bf1, col1, inv1, bv1, bufC, rowT, 32);

    if (pf) QWRITE(vA, bufN);      // waits only on this period's 16 loads

    asm volatile("s_waitcnt lgkmcnt(0)" ::: "memory");
    __builtin_amdgcn_s_barrier();
  }

#undef LOADV
#undef QWRITE
#undef PANEL
}

extern "C" void kernel_launch(void* const* d_in, const int* in_sizes, int n_in,
                              void* d_out, int out_size, void* d_ws, size_t ws_size,
                              hipStream_t stream) {
  const float* x    = (const float*)d_in[0];
  const float* kern = (const float*)d_in[1];
  const float* bias = (const float*)d_in[2];
  // d_in[3] = padding_mask: fixed act bounds + eval mode -> not in the math.

  int8_t* wq    = (int8_t*)d_ws;                            // 256 KB
  float*  invcs = (float*)((char*)d_ws + (size_t)FN * DK);  // 2 KB

  wq_quant_kernel<<<128, 256, 0, stream>>>(kern, wq, invcs);
  aqt_gemm_fused<<<GBLK, GT, 0, stream>>>(x, wq, invcs, bias, (float*)d_out);
}

// Round 18
// 111.505 us; speedup vs baseline: 1.3662x; 1.3662x over previous
//
#include <hip/hip_runtime.h>
#include <stdint.h>

typedef int   int32x4   __attribute__((ext_vector_type(4)));
typedef int   int32x16  __attribute__((ext_vector_type(16)));
typedef float floatx4   __attribute__((ext_vector_type(4)));

#define B_ROWS 131072
#define DK 512           // K (= D)
#define FN 512           // N (= F)
#define A_SCALE_F ((float)(127.0 / 6.0))

// fused-GEMM geometry: 512 blocks x 512 threads (8 waves). Per-wave ~272 unified
// regs (Bf0+Bf1+acc in AGPR, staging+misc in VGPR) -> one 8-wave block per CU.
// This is the measured optimum (110.9us): every register-cheaper or
// deeper-pipelined variant spills (R8/R10/R12/R14/R17) or thrashes L2 (R15).
#define GBLK 512
#define GT   512
#define BMS  32
#define GTILES (B_ROWS / BMS / GBLK)   // 8 (even, required by the 2-unroll)

// ---------------- prepass: quantize weights into B-fragment layout -------------
__global__ void wq_quant_kernel(const float* __restrict__ kern,  // [DK][FN]
                                int8_t* __restrict__ wq,         // [FN][DK]
                                float* __restrict__ invcs) {     // [FN]
  __shared__ float smax[256];
  __shared__ float sscale[4];
  const int c = threadIdx.x & 3;         // col within block
  const int g = threadIdx.x >> 2;        // row-group 0..63 (8 rows each)
  const int col = blockIdx.x * 4 + c;

  float m = 0.f;
#pragma unroll
  for (int i = 0; i < 8; ++i) {
    m = fmaxf(m, fabsf(kern[(size_t)(g * 8 + i) * FN + col]));
  }
  smax[threadIdx.x] = m;
  __syncthreads();
  if (threadIdx.x < 4) {
    float mm = smax[threadIdx.x];
#pragma unroll 8
    for (int g2 = 1; g2 < 64; ++g2) mm = fmaxf(mm, smax[g2 * 4 + threadIdx.x]);
    const float wb = fmaxf(mm, 1e-6f);
    const float ws = 127.f / wb;               // f32 divide, matches jnp w_scale
    sscale[threadIdx.x] = ws;
    invcs[blockIdx.x * 4 + threadIdx.x] =
        (float)(1.0 / ((double)A_SCALE_F * (double)ws));
  }
  __syncthreads();
  const float ws = sscale[c];
  uint32_t* wq32 = (uint32_t*)(wq + (size_t)col * DK);
#pragma unroll
  for (int d = 0; d < 2; ++d) {                // 8 rows -> 2 packed words
    uint32_t p = 0;
#pragma unroll
    for (int j = 0; j < 4; ++j) {
      float v = kern[(size_t)(g * 8 + d * 4 + j) * FN + col] * ws;
      v = floorf(v + 0.5f);                    // AQT round: floor(v+0.5)
      v = fminf(fmaxf(v, -127.f), 127.f);
      p |= ((uint32_t)((int)v & 255)) << (8 * j);
    }
    wq32[g * 2 + d] = p;
  }
}

// ---------------- fused GEMM: 2-deep prefetch, 8 waves, 256-VGPR budget --------
__device__ __forceinline__ uint32_t quant4(floatx4 v) {
  uint32_t p = 0;
#pragma unroll
  for (int j = 0; j < 4; ++j) {
    float q = floorf(v[j] * A_SCALE_F + 0.5f);   // AQT round: floor(v+0.5)
    q = fminf(fmaxf(q, -127.f), 127.f);
    p |= ((uint32_t)((int)q & 255)) << (8 * j);
  }
  return p;
}

__global__ __launch_bounds__(GT, 2)
void aqt_gemm_fused(const float* __restrict__ x,     // [B_ROWS][DK]
                    const int8_t* __restrict__ wq,   // [FN][DK]
                    const float* __restrict__ invcs, // [FN]
                    const float* __restrict__ bias,  // [FN]
                    float* __restrict__ out) {       // [B_ROWS][FN]
  __shared__ __align__(16) uint8_t xq[2][BMS * DK];  // 2 x 16 KB

  const int tid  = threadIdx.x;
  const int lane = tid & 63;
  const int wv   = tid >> 6;       // 0..7 -> col strip w*64
  const int l31  = lane & 31;
  const int l5   = lane >> 5;

  const int c4 = tid & 127;        // float4 col within a row
  const int rg = tid >> 7;         // 0..3 -> rows rg, rg+4, ..., rg+28

  // ---- B fragments into registers, once (256 KB, L2-hot): 2 panels ----
  const int col0 = wv * 64 + l31;
  const int col1 = col0 + 32;
  int32x4 Bf0[16], Bf1[16];
#pragma unroll
  for (int ks = 0; ks < 16; ++ks) {
    Bf0[ks] = *(const int32x4*)(wq + (size_t)col0 * DK + ks * 32 + l5 * 16);
    Bf1[ks] = *(const int32x4*)(wq + (size_t)col1 * DK + ks * 32 + l5 * 16);
  }
  const float inv0 = invcs[col0], bv0 = bias[col0];
  const float inv1 = invcs[col1], bv1 = bias[col1];

  const size_t row0 = (size_t)blockIdx.x * (GTILES * BMS);

  // issue the 8 f32 tile loads for tile starting at row rt
#define LOADV(vdst, rt)                                                       \
  {                                                                           \
    const float* xg_ = x + (size_t)(rt) * DK;                                 \
    _Pragma("unroll")                                                         \
    for (int i_ = 0; i_ < 8; ++i_)                                            \
      vdst[i_] = *(const floatx4*)(xg_ + (size_t)(i_ * 4 + rg) * DK + c4 * 4);\
  }

  // quantize 8 granules into LDS buffer (XOR-swizzled)
#define QWRITE(vsrc, bufp)                                                    \
  {                                                                           \
    _Pragma("unroll")                                                         \
    for (int i_ = 0; i_ < 8; ++i_) {                                          \
      const int r_ = i_ * 4 + rg;                                             \
      *(uint32_t*)(&(bufp)[r_ * DK + ((c4 * 4) ^ ((r_ & 31) << 4))]) =        \
          quant4(vsrc[i_]);                                                   \
    }                                                                         \
  }

  // one 32-col panel: K-loop + epilogue NT stores (acc lives only inside)
#define PANEL(Bf, colv, invv, bvv, bufp, rt)                                  \
  {                                                                           \
    int32x16 acc = (int32x16)(0);                                             \
    const uint8_t* aRow_ = (bufp) + l31 * DK;                                 \
    _Pragma("unroll")                                                         \
    for (int ks_ = 0; ks_ < 16; ++ks_) {                                      \
      int32x4 a_ = *(const int32x4*)(aRow_ + ((ks_ * 32 + l5 * 16) ^ (l31 << 4))); \
      acc = __builtin_amdgcn_mfma_i32_32x32x32_i8(a_, Bf[ks_], acc, 0, 0, 0); \
    }                                                                         \
    _Pragma("unroll")                                                         \
    for (int r_ = 0; r_ < 16; ++r_) {                                         \
      const int rowl_ = (r_ & 3) + 8 * (r_ >> 2) + 4 * l5;                    \
      __builtin_nontemporal_store((float)acc[r_] * (invv) + (bvv),            \
                                  &out[((rt) + rowl_) * FN + (colv)]);        \
    }                                                                         \
  }

  floatx4 vA[8], vB[8];

  // ---- prologue: tile 0 staged (startup stall, once); tile 1 in flight ----
  LOADV(vA, row0);
  QWRITE(vA, (&xq[0][0]));
  LOADV(vB, row0 + BMS);
  asm volatile("s_waitcnt lgkmcnt(0)" ::: "memory");
  __builtin_amdgcn_s_barrier();

#pragma unroll 1
  for (int t = 0; t < GTILES; t += 2) {
    const size_t rowT = row0 + (size_t)t * BMS;

    // even: compute buf0 (tile t); prefetch vA <- t+2; quantize vB -> buf1
    if (t + 2 < GTILES) LOADV(vA, rowT + 2 * BMS);
    PANEL(Bf0, col0, inv0, bv0, (&xq[0][0]), rowT);
    PANEL(Bf1, col1, inv1, bv1, (&xq[0][0]), rowT);
    QWRITE(vB, (&xq[1][0]));              // tile t+1 (always < GTILES)
    asm volatile("s_waitcnt lgkmcnt(0)" ::: "memory");
    __builtin_amdgcn_s_barrier();

    // odd: compute buf1 (tile t+1); prefetch vB <- t+3; quantize vA -> buf0
    if (t + 3 < GTILES) LOADV(vB, rowT + 3 * BMS);
    PANEL(Bf0, col0, inv0, bv0, (&xq[1][0]), rowT + BMS);
    PANEL(Bf1, col1, inv1, bv1, (&xq[1][0]), rowT + BMS);
    if (t + 2 < GTILES) QWRITE(vA, (&xq[0][0]));
    asm volatile("s_waitcnt lgkmcnt(0)" ::: "memory");
    __builtin_amdgcn_s_barrier();
  }

#undef LOADV
#undef QWRITE
#undef PANEL
}

extern "C" void kernel_launch(void* const* d_in, const int* in_sizes, int n_in,
                              void* d_out, int out_size, void* d_ws, size_t ws_size,
                              hipStream_t stream) {
  const float* x    = (const float*)d_in[0];
  const float* kern = (const float*)d_in[1];
  const float* bias = (const float*)d_in[2];
  // d_in[3] = padding_mask: fixed act bounds + eval mode -> not in the math.

  int8_t* wq    = (int8_t*)d_ws;                            // 256 KB
  float*  invcs = (float*)((char*)d_ws + (size_t)FN * DK);  // 2 KB

  wq_quant_kernel<<<128, 256, 0, stream>>>(kern, wq, invcs);
  aqt_gemm_fused<<<GBLK, GT, 0, stream>>>(x, wq, invcs, bias, (float*)d_out);
}